// Round 7
// baseline (383.616 us; speedup 1.0000x reference)
//
#include <hip/hip_runtime.h>

#define NN 50000
#define NE 640000
#define DF 128
#define BM 64
#define BK 32
#define BSH 7
#define BWD 128                          // nodes per bucket
#define NBKT ((NN + BWD - 1) / BWD)      // 391 buckets
#define BSTRIDE 4096                     // bucket capacity (mean 1638, +60 sigma)

__device__ inline unsigned bf16rne(float f) {
  unsigned u = __float_as_uint(f);
  return (u + 0x7fff + ((u >> 16) & 1)) >> 16;
}
__device__ inline float bflo(unsigned u) { return __uint_as_float(u << 16); }
__device__ inline float bfhi(unsigned u) { return __uint_as_float(u & 0xffff0000u); }

// ---------------- bucketed CSR build ----------------

__global__ __launch_bounds__(512) void k_zb(int* __restrict__ bfill) {
  int t = threadIdx.x;
  if (t < NBKT) bfill[t] = 0;
}

// append packed (src | dstLocal<<16) into fixed-stride bucket regions
__global__ __launch_bounds__(256) void k_bscatter(const int* __restrict__ ei, int* __restrict__ bfill,
                                                  unsigned* __restrict__ pairs) {
  int e = blockIdx.x * 256 + threadIdx.x;
  if (e >= NE) return;
  int s = ei[e];
  int d = ei[NE + e];
  int b = d >> BSH;
  int pos = atomicAdd(&bfill[b], 1);
  if (pos < BSTRIDE)
    pairs[(size_t)b * BSTRIDE + pos] = (unsigned)s | ((unsigned)(d & (BWD - 1)) << 16);
}

// scan 391 bucket counts -> global CSR bucket bases
__global__ __launch_bounds__(512) void k_bscan(const int* __restrict__ bfill, int* __restrict__ boff) {
  __shared__ int s[512];
  int t = threadIdx.x;
  int v = (t < NBKT) ? bfill[t] : 0;
  s[t] = v;
  __syncthreads();
  for (int d = 1; d < 512; d <<= 1) {
    int x = (t >= d) ? s[t - d] : 0;
    __syncthreads();
    s[t] += x;
    __syncthreads();
  }
  if (t < NBKT) boff[t] = s[t] - v;  // exclusive
  if (t == 0) boff[NBKT] = NE;
}

// one block per bucket: local count/scan in LDS, write off+dinv coalesced,
// place src into LDS stage in CSR order, flush coalesced.
__global__ __launch_bounds__(256) void k_build(const unsigned* __restrict__ pairs,
                                               const int* __restrict__ boff,
                                               int* __restrict__ off, float* __restrict__ dinv,
                                               int* __restrict__ ssrc) {
  __shared__ int lcnt[BWD];
  __shared__ int lfill[BWD];
  __shared__ int s[BWD];
  __shared__ unsigned short stage[BSTRIDE];
  int b = blockIdx.x, t = threadIdx.x;
  int e0 = boff[b], e1 = boff[b + 1];
  int n = e1 - e0;
  const unsigned* pb = pairs + (size_t)b * BSTRIDE;

  if (t < BWD) lcnt[t] = 0;
  __syncthreads();
  for (int i = t; i < n; i += 256) atomicAdd(&lcnt[pb[i] >> 16], 1);
  __syncthreads();
  int cnt = (t < BWD) ? lcnt[t] : 0;
  if (t < BWD) s[t] = cnt;
  __syncthreads();
  for (int d = 1; d < BWD; d <<= 1) {
    int x = (t >= d && t < BWD) ? s[t - d] : 0;
    __syncthreads();
    if (t < BWD) s[t] += x;
    __syncthreads();
  }
  int node = b * BWD + t;
  if (t < BWD) {
    int ex = s[t] - cnt;
    lfill[t] = ex;
    if (node < NN) {
      off[node] = e0 + ex;
      dinv[node] = rsqrtf((float)(cnt + 1));  // +1 self-loop
    }
    if (node == NN - 1) off[NN] = NE;
  }
  __syncthreads();
  for (int i = t; i < n; i += 256) {
    unsigned p = pb[i];
    int pos = atomicAdd(&lfill[p >> 16], 1);
    stage[pos] = (unsigned short)(p & 0xffffu);
  }
  __syncthreads();
  for (int i = t; i < n; i += 256) ssrc[e0 + i] = (int)stage[i];
}

// ---------------- GEMM: C_bf16[M,128] = A_f32[M,128] @ W[128,128] ----------------

__global__ __launch_bounds__(256) void k_gemm(const float* __restrict__ A,
                                              const float* __restrict__ W,
                                              unsigned* __restrict__ C) {
  __shared__ float As[BK][BM + 4];
  __shared__ float Ws[BK][DF];

  int tid = threadIdx.x;
  int brow = blockIdx.x * BM;

  int rg = tid >> 5;
  int cg = tid & 31;
  int ar = tid >> 2;
  int ac = (tid & 3) * 8;

  float4 acc[8];
#pragma unroll
  for (int r = 0; r < 8; ++r) acc[r] = make_float4(0.f, 0.f, 0.f, 0.f);

  for (int k0 = 0; k0 < DF; k0 += BK) {
    float4 a0 = make_float4(0.f, 0.f, 0.f, 0.f), a1 = a0;
    if (brow + ar < NN) {
      const float4* ap = (const float4*)(A + (size_t)(brow + ar) * DF + k0 + ac);
      a0 = ap[0];
      a1 = ap[1];
    }
    const float4* wg = (const float4*)(W + (size_t)k0 * DF);
    float4 w0 = wg[tid], w1 = wg[tid + 256], w2 = wg[tid + 512], w3 = wg[tid + 768];

    __syncthreads();

    As[ac + 0][ar] = a0.x; As[ac + 1][ar] = a0.y;
    As[ac + 2][ar] = a0.z; As[ac + 3][ar] = a0.w;
    As[ac + 4][ar] = a1.x; As[ac + 5][ar] = a1.y;
    As[ac + 6][ar] = a1.z; As[ac + 7][ar] = a1.w;

    float4* wl = (float4*)&Ws[0][0];
    wl[tid] = w0; wl[tid + 256] = w1; wl[tid + 512] = w2; wl[tid + 768] = w3;

    __syncthreads();

#pragma unroll 4
    for (int kk = 0; kk < BK; ++kk) {
      float4 av0 = *(const float4*)&As[kk][rg * 8];
      float4 av1 = *(const float4*)&As[kk][rg * 8 + 4];
      float4 wv = *(const float4*)&Ws[kk][cg * 4];
      float a_[8] = {av0.x, av0.y, av0.z, av0.w, av1.x, av1.y, av1.z, av1.w};
#pragma unroll
      for (int r = 0; r < 8; ++r) {
        acc[r].x = fmaf(a_[r], wv.x, acc[r].x);
        acc[r].y = fmaf(a_[r], wv.y, acc[r].y);
        acc[r].z = fmaf(a_[r], wv.z, acc[r].z);
        acc[r].w = fmaf(a_[r], wv.w, acc[r].w);
      }
    }
  }

#pragma unroll
  for (int r = 0; r < 8; ++r) {
    int row = brow + rg * 8 + r;
    if (row < NN) {
      uint2 p;
      p.x = bf16rne(acc[r].x) | (bf16rne(acc[r].y) << 16);
      p.y = bf16rne(acc[r].z) | (bf16rne(acc[r].w) << 16);
      *(uint2*)(C + (size_t)row * (DF / 2) + cg * 2) = p;
    }
  }
}

// ---------------- Aggregation: one wave per node; quarter-direct gathers ----------------
// Each 16-lane quarter owns one edge per iter: same-address ssrc/dinv loads
// (HW broadcast), one uint4 = full 256B bf16 row per quarter.

__global__ __launch_bounds__(256) void k_agg(const unsigned* __restrict__ h, const float* __restrict__ dinv,
                                             const int* __restrict__ off, const int* __restrict__ ssrc,
                                             const float* __restrict__ bias,
                                             float* __restrict__ out, int do_relu) {
  int gw = (blockIdx.x * 256 + threadIdx.x) >> 6;
  int lane = threadIdx.x & 63;
  if (gw >= NN) return;

  int c = lane & 15;   // 16B chunk within row
  int q = lane >> 4;   // quarter id

  float di = dinv[gw];

  float acc[8];
  {
    float w = (q == 0) ? di * di : 0.f;
    uint4 u = *((const uint4*)(h + (size_t)gw * 64) + c);
    acc[0] = bflo(u.x) * w; acc[1] = bfhi(u.x) * w;
    acc[2] = bflo(u.y) * w; acc[3] = bfhi(u.y) * w;
    acc[4] = bflo(u.z) * w; acc[5] = bfhi(u.z) * w;
    acc[6] = bflo(u.w) * w; acc[7] = bfhi(u.w) * w;
  }

  int e = off[gw], e1 = off[gw + 1];
  for (int e0 = e; e0 < e1; e0 += 4) {
    int ee = e0 + q;
    int idx = min(ee, e1 - 1);
    int sv = ssrc[idx];                          // same addr across quarter -> broadcast
    float w = (ee < e1) ? dinv[sv] * di : 0.f;   // same addr across quarter
    uint4 u = *((const uint4*)(h + (size_t)sv * 64) + c);
    acc[0] = fmaf(bflo(u.x), w, acc[0]); acc[1] = fmaf(bfhi(u.x), w, acc[1]);
    acc[2] = fmaf(bflo(u.y), w, acc[2]); acc[3] = fmaf(bfhi(u.y), w, acc[3]);
    acc[4] = fmaf(bflo(u.z), w, acc[4]); acc[5] = fmaf(bfhi(u.z), w, acc[5]);
    acc[6] = fmaf(bflo(u.w), w, acc[6]); acc[7] = fmaf(bfhi(u.w), w, acc[7]);
  }

#pragma unroll
  for (int j = 0; j < 8; ++j) {
    acc[j] += __shfl_xor(acc[j], 16);
    acc[j] += __shfl_xor(acc[j], 32);
  }

  if (q < 2) {
    int col0 = c * 8 + q * 4;
    float4 b4 = *(const float4*)(bias + col0);
    float4 o;
    o.x = acc[q * 4 + 0] + b4.x;
    o.y = acc[q * 4 + 1] + b4.y;
    o.z = acc[q * 4 + 2] + b4.z;
    o.w = acc[q * 4 + 3] + b4.w;
    if (do_relu) {
      o.x = fmaxf(o.x, 0.f); o.y = fmaxf(o.y, 0.f);
      o.z = fmaxf(o.z, 0.f); o.w = fmaxf(o.w, 0.f);
    }
    *(float4*)(out + (size_t)gw * DF + col0) = o;
  }
}

// ---------------- launcher ----------------

extern "C" void kernel_launch(void* const* d_in, const int* in_sizes, int n_in,
                              void* d_out, int out_size, void* d_ws, size_t ws_size,
                              hipStream_t stream) {
  const float* x  = (const float*)d_in[0];
  const int*   ei = (const int*)d_in[1];
  const float* W1 = (const float*)d_in[2];
  const float* b1 = (const float*)d_in[3];
  const float* W2 = (const float*)d_in[4];
  const float* b2 = (const float*)d_in[5];
  float* out = (float*)d_out;

  char* ws = (char*)d_ws;
  unsigned* hT    = (unsigned*)ws; ws += (size_t)NN * (DF / 2) * 4;       // 12.8 MB bf16 table
  unsigned* pairs = (unsigned*)ws; ws += (size_t)NBKT * BSTRIDE * 4;      // 6.4 MB bucket staging
  int*   ssrc = (int*)ws;   ws += (size_t)NE * 4;
  float* dinv = (float*)ws; ws += (size_t)NN * 4;
  int*   off  = (int*)ws;   ws += (size_t)(NN + 1) * 4;
  int*   bfill= (int*)ws;   ws += (size_t)NBKT * 4;
  int*   boff = (int*)ws;   ws += (size_t)(NBKT + 1) * 4;
  float* act = out;  // layer-1 activation (f32) in d_out; fully rewritten by final agg

  k_zb<<<1, 512, 0, stream>>>(bfill);
  k_bscatter<<<(NE + 255) / 256, 256, 0, stream>>>(ei, bfill, pairs);
  k_bscan<<<1, 512, 0, stream>>>(bfill, boff);
  k_build<<<NBKT, 256, 0, stream>>>(pairs, boff, off, dinv, ssrc);

  k_gemm<<<(NN + BM - 1) / BM, 256, 0, stream>>>(x, W1, hT);
  k_agg<<<(NN * 64 + 255) / 256, 256, 0, stream>>>(hT, dinv, off, ssrc, b1, act, 1);
  k_gemm<<<(NN + BM - 1) / BM, 256, 0, stream>>>(act, W2, hT);
  k_agg<<<(NN * 64 + 255) / 256, 256, 0, stream>>>(hT, dinv, off, ssrc, b2, out, 0);
}

// Round 8
// 196.011 us; speedup vs baseline: 1.9571x; 1.9571x over previous
//
#include <hip/hip_runtime.h>

#define NN 50000
#define NE 640000
#define DF 128
#define BM 64
#define BK 32
#define BSH 7
#define BWD 128                          // nodes per bucket
#define NBKT ((NN + BWD - 1) / BWD)      // 391 buckets
#define NSUB 16                          // sub-slot counters per bucket (contention shard)
#define SUBCAP 256                       // capacity per sub-slot (mean 102)
#define BSTRIDE (NSUB * SUBCAP)          // 4096 per bucket

__device__ inline unsigned bf16rne(float f) {
  unsigned u = __float_as_uint(f);
  return (u + 0x7fff + ((u >> 16) & 1)) >> 16;
}
__device__ inline float bflo(unsigned u) { return __uint_as_float(u << 16); }
__device__ inline float bfhi(unsigned u) { return __uint_as_float(u & 0xffff0000u); }

// ---------------- bucketed CSR build ----------------

__global__ __launch_bounds__(256) void k_zb(int* __restrict__ bfill) {
  int t = blockIdx.x * 256 + threadIdx.x;
  if (t < NBKT * NSUB) bfill[t] = 0;
}

// append packed (src | dstLocal<<16) into per-bucket sub-slot regions
__global__ __launch_bounds__(256) void k_bscatter(const int* __restrict__ ei, int* __restrict__ bfill,
                                                  unsigned* __restrict__ pairs) {
  int e = blockIdx.x * 256 + threadIdx.x;
  if (e >= NE) return;
  int s = ei[e];
  int d = ei[NE + e];
  int b = d >> BSH;
  int sub = e & (NSUB - 1);
  int pos = atomicAdd(&bfill[b * NSUB + sub], 1);
  if (pos < SUBCAP)
    pairs[(size_t)b * BSTRIDE + sub * SUBCAP + pos] =
        (unsigned)s | ((unsigned)(d & (BWD - 1)) << 16);
}

// scan per-bucket totals -> global CSR bucket bases
__global__ __launch_bounds__(512) void k_bscan(const int* __restrict__ bfill, int* __restrict__ boff) {
  __shared__ int s[512];
  int t = threadIdx.x;
  int v = 0;
  if (t < NBKT) {
#pragma unroll
    for (int k = 0; k < NSUB; ++k) v += min(bfill[t * NSUB + k], SUBCAP);
  }
  s[t] = v;
  __syncthreads();
  for (int d = 1; d < 512; d <<= 1) {
    int x = (t >= d) ? s[t - d] : 0;
    __syncthreads();
    s[t] += x;
    __syncthreads();
  }
  if (t < NBKT) boff[t] = s[t] - v;  // exclusive
  if (t == 0) boff[NBKT] = NE;
}

// one block per bucket: LDS histogram -> scan -> coalesced off/dinv/ssrc
__global__ __launch_bounds__(256) void k_build(const unsigned* __restrict__ pairs,
                                               const int* __restrict__ bfill,
                                               const int* __restrict__ boff,
                                               int* __restrict__ off, float* __restrict__ dinv,
                                               int* __restrict__ ssrc) {
  __shared__ int lcnt[BWD];
  __shared__ int lfill[BWD];
  __shared__ int s[BWD];
  __shared__ int csub[NSUB];
  __shared__ unsigned short stage[BSTRIDE];
  int b = blockIdx.x, t = threadIdx.x;
  int e0 = boff[b];
  int n = boff[b + 1] - e0;
  const unsigned* pb = pairs + (size_t)b * BSTRIDE;

  if (t < BWD) lcnt[t] = 0;
  if (t < NSUB) csub[t] = min(bfill[b * NSUB + t], SUBCAP);
  __syncthreads();

#pragma unroll
  for (int k = 0; k < NSUB; ++k) {
    int nk = csub[k];
    const unsigned* ps = pb + k * SUBCAP;
    for (int i = t; i < nk; i += 256) atomicAdd(&lcnt[ps[i] >> 16], 1);
  }
  __syncthreads();

  int cnt = (t < BWD) ? lcnt[t] : 0;
  if (t < BWD) s[t] = cnt;
  __syncthreads();
  for (int d = 1; d < BWD; d <<= 1) {
    int x = (t >= d && t < BWD) ? s[t - d] : 0;
    __syncthreads();
    if (t < BWD) s[t] += x;
    __syncthreads();
  }
  int node = b * BWD + t;
  if (t < BWD) {
    int ex = s[t] - cnt;
    lfill[t] = ex;
    if (node < NN) {
      off[node] = e0 + ex;
      dinv[node] = rsqrtf((float)(cnt + 1));  // +1 self-loop
    }
    if (node == NN - 1) off[NN] = NE;
  }
  __syncthreads();

#pragma unroll
  for (int k = 0; k < NSUB; ++k) {
    int nk = csub[k];
    const unsigned* ps = pb + k * SUBCAP;
    for (int i = t; i < nk; i += 256) {
      unsigned p = ps[i];
      int pos = atomicAdd(&lfill[p >> 16], 1);
      stage[pos] = (unsigned short)(p & 0xffffu);  // src < 50000 fits 16 bits
    }
  }
  __syncthreads();
  for (int i = t; i < n; i += 256) ssrc[e0 + i] = (int)stage[i];
}

// ---------------- GEMM: C_bf16[M,128] = A_f32[M,128] @ W[128,128] ----------------

__global__ __launch_bounds__(256) void k_gemm(const float* __restrict__ A,
                                              const float* __restrict__ W,
                                              unsigned* __restrict__ C) {
  __shared__ float As[BK][BM + 4];
  __shared__ float Ws[BK][DF];

  int tid = threadIdx.x;
  int brow = blockIdx.x * BM;

  int rg = tid >> 5;
  int cg = tid & 31;
  int ar = tid >> 2;
  int ac = (tid & 3) * 8;

  float4 acc[8];
#pragma unroll
  for (int r = 0; r < 8; ++r) acc[r] = make_float4(0.f, 0.f, 0.f, 0.f);

  for (int k0 = 0; k0 < DF; k0 += BK) {
    float4 a0 = make_float4(0.f, 0.f, 0.f, 0.f), a1 = a0;
    if (brow + ar < NN) {
      const float4* ap = (const float4*)(A + (size_t)(brow + ar) * DF + k0 + ac);
      a0 = ap[0];
      a1 = ap[1];
    }
    const float4* wg = (const float4*)(W + (size_t)k0 * DF);
    float4 w0 = wg[tid], w1 = wg[tid + 256], w2 = wg[tid + 512], w3 = wg[tid + 768];

    __syncthreads();

    As[ac + 0][ar] = a0.x; As[ac + 1][ar] = a0.y;
    As[ac + 2][ar] = a0.z; As[ac + 3][ar] = a0.w;
    As[ac + 4][ar] = a1.x; As[ac + 5][ar] = a1.y;
    As[ac + 6][ar] = a1.z; As[ac + 7][ar] = a1.w;

    float4* wl = (float4*)&Ws[0][0];
    wl[tid] = w0; wl[tid + 256] = w1; wl[tid + 512] = w2; wl[tid + 768] = w3;

    __syncthreads();

#pragma unroll 4
    for (int kk = 0; kk < BK; ++kk) {
      float4 av0 = *(const float4*)&As[kk][rg * 8];
      float4 av1 = *(const float4*)&As[kk][rg * 8 + 4];
      float4 wv = *(const float4*)&Ws[kk][cg * 4];
      float a_[8] = {av0.x, av0.y, av0.z, av0.w, av1.x, av1.y, av1.z, av1.w};
#pragma unroll
      for (int r = 0; r < 8; ++r) {
        acc[r].x = fmaf(a_[r], wv.x, acc[r].x);
        acc[r].y = fmaf(a_[r], wv.y, acc[r].y);
        acc[r].z = fmaf(a_[r], wv.z, acc[r].z);
        acc[r].w = fmaf(a_[r], wv.w, acc[r].w);
      }
    }
  }

#pragma unroll
  for (int r = 0; r < 8; ++r) {
    int row = brow + rg * 8 + r;
    if (row < NN) {
      uint2 p;
      p.x = bf16rne(acc[r].x) | (bf16rne(acc[r].y) << 16);
      p.y = bf16rne(acc[r].z) | (bf16rne(acc[r].w) << 16);
      *(uint2*)(C + (size_t)row * (DF / 2) + cg * 2) = p;
    }
  }
}

// ---------------- Aggregation: one wave per node; quarter-direct gathers ----------------

__global__ __launch_bounds__(256) void k_agg(const unsigned* __restrict__ h, const float* __restrict__ dinv,
                                             const int* __restrict__ off, const int* __restrict__ ssrc,
                                             const float* __restrict__ bias,
                                             float* __restrict__ out, int do_relu) {
  int gw = (blockIdx.x * 256 + threadIdx.x) >> 6;
  int lane = threadIdx.x & 63;
  if (gw >= NN) return;

  int c = lane & 15;   // 16B chunk within row
  int q = lane >> 4;   // quarter id

  float di = dinv[gw];

  float acc[8];
  {
    float w = (q == 0) ? di * di : 0.f;
    uint4 u = *((const uint4*)(h + (size_t)gw * 64) + c);
    acc[0] = bflo(u.x) * w; acc[1] = bfhi(u.x) * w;
    acc[2] = bflo(u.y) * w; acc[3] = bfhi(u.y) * w;
    acc[4] = bflo(u.z) * w; acc[5] = bfhi(u.z) * w;
    acc[6] = bflo(u.w) * w; acc[7] = bfhi(u.w) * w;
  }

  int e = off[gw], e1 = off[gw + 1];
  for (int e0 = e; e0 < e1; e0 += 4) {
    int ee = e0 + q;
    int idx = min(ee, e1 - 1);
    int sv = ssrc[idx];                          // same addr across quarter -> broadcast
    float w = (ee < e1) ? dinv[sv] * di : 0.f;
    uint4 u = *((const uint4*)(h + (size_t)sv * 64) + c);
    acc[0] = fmaf(bflo(u.x), w, acc[0]); acc[1] = fmaf(bfhi(u.x), w, acc[1]);
    acc[2] = fmaf(bflo(u.y), w, acc[2]); acc[3] = fmaf(bfhi(u.y), w, acc[3]);
    acc[4] = fmaf(bflo(u.z), w, acc[4]); acc[5] = fmaf(bfhi(u.z), w, acc[5]);
    acc[6] = fmaf(bflo(u.w), w, acc[6]); acc[7] = fmaf(bfhi(u.w), w, acc[7]);
  }

#pragma unroll
  for (int j = 0; j < 8; ++j) {
    acc[j] += __shfl_xor(acc[j], 16);
    acc[j] += __shfl_xor(acc[j], 32);
  }

  if (q < 2) {
    int col0 = c * 8 + q * 4;
    float4 b4 = *(const float4*)(bias + col0);
    float4 o;
    o.x = acc[q * 4 + 0] + b4.x;
    o.y = acc[q * 4 + 1] + b4.y;
    o.z = acc[q * 4 + 2] + b4.z;
    o.w = acc[q * 4 + 3] + b4.w;
    if (do_relu) {
      o.x = fmaxf(o.x, 0.f); o.y = fmaxf(o.y, 0.f);
      o.z = fmaxf(o.z, 0.f); o.w = fmaxf(o.w, 0.f);
    }
    *(float4*)(out + (size_t)gw * DF + col0) = o;
  }
}

// ---------------- launcher ----------------

extern "C" void kernel_launch(void* const* d_in, const int* in_sizes, int n_in,
                              void* d_out, int out_size, void* d_ws, size_t ws_size,
                              hipStream_t stream) {
  const float* x  = (const float*)d_in[0];
  const int*   ei = (const int*)d_in[1];
  const float* W1 = (const float*)d_in[2];
  const float* b1 = (const float*)d_in[3];
  const float* W2 = (const float*)d_in[4];
  const float* b2 = (const float*)d_in[5];
  float* out = (float*)d_out;

  char* ws = (char*)d_ws;
  unsigned* hT    = (unsigned*)ws; ws += (size_t)NN * (DF / 2) * 4;   // 12.8 MB bf16 table
  unsigned* pairs = (unsigned*)ws; ws += (size_t)NBKT * BSTRIDE * 4;  // 6.4 MB bucket staging
  int*   ssrc = (int*)ws;   ws += (size_t)NE * 4;
  float* dinv = (float*)ws; ws += (size_t)NN * 4;
  int*   off  = (int*)ws;   ws += (size_t)(NN + 1) * 4;
  int*   bfill= (int*)ws;   ws += (size_t)NBKT * NSUB * 4;
  int*   boff = (int*)ws;   ws += (size_t)(NBKT + 1) * 4;
  float* act = out;  // layer-1 activation (f32) in d_out; fully rewritten by final agg

  k_zb<<<(NBKT * NSUB + 255) / 256, 256, 0, stream>>>(bfill);
  k_bscatter<<<(NE + 255) / 256, 256, 0, stream>>>(ei, bfill, pairs);
  k_bscan<<<1, 512, 0, stream>>>(bfill, boff);
  k_build<<<NBKT, 256, 0, stream>>>(pairs, bfill, boff, off, dinv, ssrc);

  k_gemm<<<(NN + BM - 1) / BM, 256, 0, stream>>>(x, W1, hT);
  k_agg<<<(NN * 64 + 255) / 256, 256, 0, stream>>>(hT, dinv, off, ssrc, b1, act, 1);
  k_gemm<<<(NN + BM - 1) / BM, 256, 0, stream>>>(act, W2, hT);
  k_agg<<<(NN * 64 + 255) / 256, 256, 0, stream>>>(hT, dinv, off, ssrc, b2, out, 0);
}

// Round 9
// 186.627 us; speedup vs baseline: 2.0555x; 1.0503x over previous
//
#include <hip/hip_runtime.h>

#define NN 50000
#define NE 640000
#define DF 128
#define BM 64
#define BK 32
#define BSH 7
#define BWD 128                          // nodes per bucket
#define NBKT ((NN + BWD - 1) / BWD)      // 391 buckets
#define NSUB 16                          // sub-slot counters per bucket
#define SUBCAP 256                       // capacity per sub-slot (mean 102)
#define BSTRIDE (NSUB * SUBCAP)          // 4096 per bucket
#define CPAD 16                          // ints per counter: one 64B line each

__device__ inline unsigned bf16rne(float f) {
  unsigned u = __float_as_uint(f);
  return (u + 0x7fff + ((u >> 16) & 1)) >> 16;
}
__device__ inline float bflo(unsigned u) { return __uint_as_float(u << 16); }
__device__ inline float bfhi(unsigned u) { return __uint_as_float(u & 0xffff0000u); }

// ---------------- bucketed CSR build ----------------

__global__ __launch_bounds__(256) void k_zb(int* __restrict__ bfill) {
  int t = blockIdx.x * 256 + threadIdx.x;
  if (t < NBKT * NSUB * CPAD) bfill[t] = 0;
}

// append packed (src | dstLocal<<16) into per-bucket sub-slot regions.
// counters padded to one per 64B line -> low line-level RMW contention.
__global__ __launch_bounds__(256) void k_bscatter(const int* __restrict__ ei, int* __restrict__ bfill,
                                                  unsigned* __restrict__ pairs) {
  int e = blockIdx.x * 256 + threadIdx.x;
  if (e >= NE) return;
  int s = ei[e];
  int d = ei[NE + e];
  int b = d >> BSH;
  int sub = e & (NSUB - 1);
  int pos = atomicAdd(&bfill[(b * NSUB + sub) * CPAD], 1);
  if (pos < SUBCAP)
    pairs[(size_t)b * BSTRIDE + sub * SUBCAP + pos] =
        (unsigned)s | ((unsigned)(d & (BWD - 1)) << 16);
}

// scan per-bucket totals -> global CSR bucket bases
__global__ __launch_bounds__(512) void k_bscan(const int* __restrict__ bfill, int* __restrict__ boff) {
  __shared__ int s[512];
  int t = threadIdx.x;
  int v = 0;
  if (t < NBKT) {
#pragma unroll
    for (int k = 0; k < NSUB; ++k) v += min(bfill[(t * NSUB + k) * CPAD], SUBCAP);
  }
  s[t] = v;
  __syncthreads();
  for (int d = 1; d < 512; d <<= 1) {
    int x = (t >= d) ? s[t - d] : 0;
    __syncthreads();
    s[t] += x;
    __syncthreads();
  }
  if (t < NBKT) boff[t] = s[t] - v;  // exclusive
  if (t == 0) boff[NBKT] = NE;
}

// one block per bucket: LDS histogram -> scan -> coalesced off/dinv/ssrc
__global__ __launch_bounds__(256) void k_build(const unsigned* __restrict__ pairs,
                                               const int* __restrict__ bfill,
                                               const int* __restrict__ boff,
                                               int* __restrict__ off, float* __restrict__ dinv,
                                               int* __restrict__ ssrc) {
  __shared__ int lcnt[BWD];
  __shared__ int lfill[BWD];
  __shared__ int s[BWD];
  __shared__ int csub[NSUB];
  __shared__ unsigned short stage[BSTRIDE];
  int b = blockIdx.x, t = threadIdx.x;
  int e0 = boff[b];
  int n = boff[b + 1] - e0;
  const unsigned* pb = pairs + (size_t)b * BSTRIDE;

  if (t < BWD) lcnt[t] = 0;
  if (t < NSUB) csub[t] = min(bfill[(b * NSUB + t) * CPAD], SUBCAP);
  __syncthreads();

#pragma unroll
  for (int k = 0; k < NSUB; ++k) {
    int nk = csub[k];
    const unsigned* ps = pb + k * SUBCAP;
    for (int i = t; i < nk; i += 256) atomicAdd(&lcnt[ps[i] >> 16], 1);
  }
  __syncthreads();

  int cnt = (t < BWD) ? lcnt[t] : 0;
  if (t < BWD) s[t] = cnt;
  __syncthreads();
  for (int d = 1; d < BWD; d <<= 1) {
    int x = (t >= d && t < BWD) ? s[t - d] : 0;
    __syncthreads();
    if (t < BWD) s[t] += x;
    __syncthreads();
  }
  int node = b * BWD + t;
  if (t < BWD) {
    int ex = s[t] - cnt;
    lfill[t] = ex;
    if (node < NN) {
      off[node] = e0 + ex;
      dinv[node] = rsqrtf((float)(cnt + 1));  // +1 self-loop
    }
    if (node == NN - 1) off[NN] = NE;
  }
  __syncthreads();

#pragma unroll
  for (int k = 0; k < NSUB; ++k) {
    int nk = csub[k];
    const unsigned* ps = pb + k * SUBCAP;
    for (int i = t; i < nk; i += 256) {
      unsigned p = ps[i];
      int pos = atomicAdd(&lfill[p >> 16], 1);
      stage[pos] = (unsigned short)(p & 0xffffu);  // src < 50000 fits 16 bits
    }
  }
  __syncthreads();
  for (int i = t; i < n; i += 256) ssrc[e0 + i] = (int)stage[i];
}

// ---------------- GEMM: C_bf16[M,128] = A_f32[M,128] @ W[128,128] ----------------

__global__ __launch_bounds__(256) void k_gemm(const float* __restrict__ A,
                                              const float* __restrict__ W,
                                              unsigned* __restrict__ C) {
  __shared__ float As[BK][BM + 4];
  __shared__ float Ws[BK][DF];

  int tid = threadIdx.x;
  int brow = blockIdx.x * BM;

  int rg = tid >> 5;
  int cg = tid & 31;
  int ar = tid >> 2;
  int ac = (tid & 3) * 8;

  float4 acc[8];
#pragma unroll
  for (int r = 0; r < 8; ++r) acc[r] = make_float4(0.f, 0.f, 0.f, 0.f);

  for (int k0 = 0; k0 < DF; k0 += BK) {
    float4 a0 = make_float4(0.f, 0.f, 0.f, 0.f), a1 = a0;
    if (brow + ar < NN) {
      const float4* ap = (const float4*)(A + (size_t)(brow + ar) * DF + k0 + ac);
      a0 = ap[0];
      a1 = ap[1];
    }
    const float4* wg = (const float4*)(W + (size_t)k0 * DF);
    float4 w0 = wg[tid], w1 = wg[tid + 256], w2 = wg[tid + 512], w3 = wg[tid + 768];

    __syncthreads();

    As[ac + 0][ar] = a0.x; As[ac + 1][ar] = a0.y;
    As[ac + 2][ar] = a0.z; As[ac + 3][ar] = a0.w;
    As[ac + 4][ar] = a1.x; As[ac + 5][ar] = a1.y;
    As[ac + 6][ar] = a1.z; As[ac + 7][ar] = a1.w;

    float4* wl = (float4*)&Ws[0][0];
    wl[tid] = w0; wl[tid + 256] = w1; wl[tid + 512] = w2; wl[tid + 768] = w3;

    __syncthreads();

#pragma unroll 4
    for (int kk = 0; kk < BK; ++kk) {
      float4 av0 = *(const float4*)&As[kk][rg * 8];
      float4 av1 = *(const float4*)&As[kk][rg * 8 + 4];
      float4 wv = *(const float4*)&Ws[kk][cg * 4];
      float a_[8] = {av0.x, av0.y, av0.z, av0.w, av1.x, av1.y, av1.z, av1.w};
#pragma unroll
      for (int r = 0; r < 8; ++r) {
        acc[r].x = fmaf(a_[r], wv.x, acc[r].x);
        acc[r].y = fmaf(a_[r], wv.y, acc[r].y);
        acc[r].z = fmaf(a_[r], wv.z, acc[r].z);
        acc[r].w = fmaf(a_[r], wv.w, acc[r].w);
      }
    }
  }

#pragma unroll
  for (int r = 0; r < 8; ++r) {
    int row = brow + rg * 8 + r;
    if (row < NN) {
      uint2 p;
      p.x = bf16rne(acc[r].x) | (bf16rne(acc[r].y) << 16);
      p.y = bf16rne(acc[r].z) | (bf16rne(acc[r].w) << 16);
      *(uint2*)(C + (size_t)row * (DF / 2) + cg * 2) = p;
    }
  }
}

// ---------------- Aggregation: one wave per node; 2 quarter-gathers in flight ----------------

__global__ __launch_bounds__(256) void k_agg(const unsigned* __restrict__ h, const float* __restrict__ dinv,
                                             const int* __restrict__ off, const int* __restrict__ ssrc,
                                             const float* __restrict__ bias,
                                             float* __restrict__ out, int do_relu) {
  int gw = (blockIdx.x * 256 + threadIdx.x) >> 6;
  int lane = threadIdx.x & 63;
  if (gw >= NN) return;

  int c = lane & 15;   // 16B chunk within row
  int q = lane >> 4;   // quarter id

  float di = dinv[gw];

  float acc[8];
  {
    float w = (q == 0) ? di * di : 0.f;
    uint4 u = *((const uint4*)(h + (size_t)gw * 64) + c);
    acc[0] = bflo(u.x) * w; acc[1] = bfhi(u.x) * w;
    acc[2] = bflo(u.y) * w; acc[3] = bfhi(u.y) * w;
    acc[4] = bflo(u.z) * w; acc[5] = bfhi(u.z) * w;
    acc[6] = bflo(u.w) * w; acc[7] = bfhi(u.w) * w;
  }

  int e = off[gw], e1 = off[gw + 1];
  int last = e1 - 1;
  for (int e0 = e; e0 < e1; e0 += 8) {
    int ea = e0 + q;
    int eb = e0 + 4 + q;
    int ia = min(ea, last), ib = min(eb, last);
    int sa = ssrc[ia];                         // same addr across quarter -> broadcast
    int sb = ssrc[ib];
    float wa = (ea < e1) ? dinv[sa] * di : 0.f;
    float wb = (eb < e1) ? dinv[sb] * di : 0.f;
    uint4 ua = *((const uint4*)(h + (size_t)sa * 64) + c);
    uint4 ub = *((const uint4*)(h + (size_t)sb * 64) + c);
    acc[0] = fmaf(bflo(ua.x), wa, acc[0]); acc[1] = fmaf(bfhi(ua.x), wa, acc[1]);
    acc[2] = fmaf(bflo(ua.y), wa, acc[2]); acc[3] = fmaf(bfhi(ua.y), wa, acc[3]);
    acc[4] = fmaf(bflo(ua.z), wa, acc[4]); acc[5] = fmaf(bfhi(ua.z), wa, acc[5]);
    acc[6] = fmaf(bflo(ua.w), wa, acc[6]); acc[7] = fmaf(bfhi(ua.w), wa, acc[7]);
    acc[0] = fmaf(bflo(ub.x), wb, acc[0]); acc[1] = fmaf(bfhi(ub.x), wb, acc[1]);
    acc[2] = fmaf(bflo(ub.y), wb, acc[2]); acc[3] = fmaf(bfhi(ub.y), wb, acc[3]);
    acc[4] = fmaf(bflo(ub.z), wb, acc[4]); acc[5] = fmaf(bfhi(ub.z), wb, acc[5]);
    acc[6] = fmaf(bflo(ub.w), wb, acc[6]); acc[7] = fmaf(bfhi(ub.w), wb, acc[7]);
  }

#pragma unroll
  for (int j = 0; j < 8; ++j) {
    acc[j] += __shfl_xor(acc[j], 16);
    acc[j] += __shfl_xor(acc[j], 32);
  }

  if (q < 2) {
    int col0 = c * 8 + q * 4;
    float4 b4 = *(const float4*)(bias + col0);
    float4 o;
    o.x = acc[q * 4 + 0] + b4.x;
    o.y = acc[q * 4 + 1] + b4.y;
    o.z = acc[q * 4 + 2] + b4.z;
    o.w = acc[q * 4 + 3] + b4.w;
    if (do_relu) {
      o.x = fmaxf(o.x, 0.f); o.y = fmaxf(o.y, 0.f);
      o.z = fmaxf(o.z, 0.f); o.w = fmaxf(o.w, 0.f);
    }
    *(float4*)(out + (size_t)gw * DF + col0) = o;
  }
}

// ---------------- launcher ----------------

extern "C" void kernel_launch(void* const* d_in, const int* in_sizes, int n_in,
                              void* d_out, int out_size, void* d_ws, size_t ws_size,
                              hipStream_t stream) {
  const float* x  = (const float*)d_in[0];
  const int*   ei = (const int*)d_in[1];
  const float* W1 = (const float*)d_in[2];
  const float* b1 = (const float*)d_in[3];
  const float* W2 = (const float*)d_in[4];
  const float* b2 = (const float*)d_in[5];
  float* out = (float*)d_out;

  char* ws = (char*)d_ws;
  unsigned* hT    = (unsigned*)ws; ws += (size_t)NN * (DF / 2) * 4;   // 12.8 MB bf16 table
  unsigned* pairs = (unsigned*)ws; ws += (size_t)NBKT * BSTRIDE * 4;  // 6.4 MB bucket staging
  int*   ssrc = (int*)ws;   ws += (size_t)NE * 4;
  float* dinv = (float*)ws; ws += (size_t)NN * 4;
  int*   off  = (int*)ws;   ws += (size_t)(NN + 1) * 4;
  int*   bfill= (int*)ws;   ws += (size_t)NBKT * NSUB * CPAD * 4;     // 400 KB padded counters
  int*   boff = (int*)ws;   ws += (size_t)(NBKT + 1) * 4;
  float* act = out;  // layer-1 activation (f32) in d_out; fully rewritten by final agg

  k_zb<<<(NBKT * NSUB * CPAD + 255) / 256, 256, 0, stream>>>(bfill);
  k_bscatter<<<(NE + 255) / 256, 256, 0, stream>>>(ei, bfill, pairs);
  k_bscan<<<1, 512, 0, stream>>>(bfill, boff);
  k_build<<<NBKT, 256, 0, stream>>>(pairs, bfill, boff, off, dinv, ssrc);

  k_gemm<<<(NN + BM - 1) / BM, 256, 0, stream>>>(x, W1, hT);
  k_agg<<<(NN * 64 + 255) / 256, 256, 0, stream>>>(hT, dinv, off, ssrc, b1, act, 1);
  k_gemm<<<(NN + BM - 1) / BM, 256, 0, stream>>>(act, W2, hT);
  k_agg<<<(NN * 64 + 255) / 256, 256, 0, stream>>>(hT, dinv, off, ssrc, b2, out, 0);
}

// Round 10
// 166.300 us; speedup vs baseline: 2.3068x; 1.1222x over previous
//
#include <hip/hip_runtime.h>

#define NN 50000
#define NE 640000
#define DF 128
#define BM 64
#define BK 32
#define BSH 7
#define BWD 128                          // nodes per bucket
#define NBKT ((NN + BWD - 1) / BWD)      // 391 buckets
#define BSTRIDE 4096                     // per-bucket capacity (mean 1638, +60 sigma)
#define CPAD 16                          // ints per global counter: one 64B line each
#define EPB 8192                         // edges per bscatter block
#define TPB 512

__device__ inline unsigned bf16rne(float f) {
  unsigned u = __float_as_uint(f);
  return (u + 0x7fff + ((u >> 16) & 1)) >> 16;
}
__device__ inline float bflo(unsigned u) { return __uint_as_float(u << 16); }
__device__ inline float bfhi(unsigned u) { return __uint_as_float(u & 0xffff0000u); }

// ---------------- bucketed CSR build ----------------

__global__ __launch_bounds__(512) void k_zb(int* __restrict__ gfill) {
  for (int i = threadIdx.x; i < NBKT * CPAD; i += 512) gfill[i] = 0;
}

// LDS-staged scatter: per block, histogram 8192 edges over 391 buckets in LDS,
// reserve global ranges with ONE atomic per (block,bucket), flush bucket-grouped
// chunks (mean 21 contiguous words) -> low line-level contention + dense writes.
__global__ __launch_bounds__(512) void k_bscatter(const int* __restrict__ ei, int* __restrict__ gfill,
                                                  unsigned* __restrict__ pairs) {
  __shared__ int cnt[NBKT];       // per-bucket local start (after scan)
  __shared__ int cur[NBKT];       // append cursor
  __shared__ int gbase[NBKT];     // reserved global base
  __shared__ int scan[TPB];
  __shared__ unsigned stage[EPB];
  int t = threadIdx.x;
  int e0 = blockIdx.x * EPB;

  for (int i = t; i < NBKT; i += TPB) cnt[i] = 0;
  __syncthreads();

  unsigned pk[16];
  int bk[16];
#pragma unroll
  for (int i = 0; i < 16; ++i) {
    int e = e0 + i * TPB + t;
    if (e < NE) {
      int s = ei[e], d = ei[NE + e];
      bk[i] = d >> BSH;
      pk[i] = (unsigned)s | ((unsigned)(d & (BWD - 1)) << 16);
      atomicAdd(&cnt[bk[i]], 1);
    } else {
      bk[i] = -1;
    }
  }
  __syncthreads();

  int v = (t < NBKT) ? cnt[t] : 0;
  scan[t] = v;
  __syncthreads();
  for (int d = 1; d < TPB; d <<= 1) {
    int x = (t >= d) ? scan[t - d] : 0;
    __syncthreads();
    scan[t] += x;
    __syncthreads();
  }
  if (t < NBKT) {
    int start = scan[t] - v;  // exclusive
    cnt[t] = start;
    cur[t] = start;
    gbase[t] = (v > 0) ? atomicAdd(&gfill[t * CPAD], v) : 0;
  }
  __syncthreads();

#pragma unroll
  for (int i = 0; i < 16; ++i) {
    if (bk[i] >= 0) {
      int pos = atomicAdd(&cur[bk[i]], 1);
      stage[pos] = pk[i];
    }
  }
  __syncthreads();

  // flush: wave w copies buckets w, w+8, ... (chunk = [cnt[b], cur[b]) in stage)
  int wv = t >> 6, ln = t & 63;
  for (int b = wv; b < NBKT; b += 8) {
    int start = cnt[b];
    int end = cur[b];
    int gb = gbase[b];
    unsigned* pb = pairs + (size_t)b * BSTRIDE;
    for (int i = start + ln; i < end; i += 64) {
      int go = gb + (i - start);
      if (go < BSTRIDE) pb[go] = stage[i];
    }
  }
}

// scan per-bucket totals -> global CSR bucket bases
__global__ __launch_bounds__(512) void k_bscan(const int* __restrict__ gfill, int* __restrict__ boff) {
  __shared__ int s[512];
  int t = threadIdx.x;
  int v = (t < NBKT) ? min(gfill[t * CPAD], BSTRIDE) : 0;
  s[t] = v;
  __syncthreads();
  for (int d = 1; d < 512; d <<= 1) {
    int x = (t >= d) ? s[t - d] : 0;
    __syncthreads();
    s[t] += x;
    __syncthreads();
  }
  if (t < NBKT) boff[t] = s[t] - v;  // exclusive
  if (t == 511) boff[NBKT] = s[511];
}

// one block per bucket: LDS histogram -> scan -> coalesced off/dinv/ssrc
__global__ __launch_bounds__(256) void k_build(const unsigned* __restrict__ pairs,
                                               const int* __restrict__ boff,
                                               int* __restrict__ off, float* __restrict__ dinv,
                                               int* __restrict__ ssrc) {
  __shared__ int lcnt[BWD];
  __shared__ int lfill[BWD];
  __shared__ int s[BWD];
  __shared__ unsigned short stage[BSTRIDE];
  int b = blockIdx.x, t = threadIdx.x;
  int e0 = boff[b];
  int n = boff[b + 1] - e0;
  const unsigned* pb = pairs + (size_t)b * BSTRIDE;

  if (t < BWD) lcnt[t] = 0;
  __syncthreads();
  for (int i = t; i < n; i += 256) atomicAdd(&lcnt[pb[i] >> 16], 1);
  __syncthreads();

  int cnt = (t < BWD) ? lcnt[t] : 0;
  if (t < BWD) s[t] = cnt;
  __syncthreads();
  for (int d = 1; d < BWD; d <<= 1) {
    int x = (t >= d && t < BWD) ? s[t - d] : 0;
    __syncthreads();
    if (t < BWD) s[t] += x;
    __syncthreads();
  }
  int node = b * BWD + t;
  if (t < BWD) {
    int ex = s[t] - cnt;
    lfill[t] = ex;
    if (node < NN) {
      off[node] = e0 + ex;
      dinv[node] = rsqrtf((float)(cnt + 1));  // +1 self-loop
    }
    if (node == NN - 1) off[NN] = NE;
  }
  __syncthreads();

  for (int i = t; i < n; i += 256) {
    unsigned p = pb[i];
    int pos = atomicAdd(&lfill[p >> 16], 1);
    stage[pos] = (unsigned short)(p & 0xffffu);  // src < 50000 fits 16 bits
  }
  __syncthreads();
  for (int i = t; i < n; i += 256) ssrc[e0 + i] = (int)stage[i];
}

// ---------------- GEMM: C_bf16[M,128] = A_f32[M,128] @ W[128,128] ----------------

__global__ __launch_bounds__(256) void k_gemm(const float* __restrict__ A,
                                              const float* __restrict__ W,
                                              unsigned* __restrict__ C) {
  __shared__ float As[BK][BM + 4];
  __shared__ float Ws[BK][DF];

  int tid = threadIdx.x;
  int brow = blockIdx.x * BM;

  int rg = tid >> 5;
  int cg = tid & 31;
  int ar = tid >> 2;
  int ac = (tid & 3) * 8;

  float4 acc[8];
#pragma unroll
  for (int r = 0; r < 8; ++r) acc[r] = make_float4(0.f, 0.f, 0.f, 0.f);

  for (int k0 = 0; k0 < DF; k0 += BK) {
    float4 a0 = make_float4(0.f, 0.f, 0.f, 0.f), a1 = a0;
    if (brow + ar < NN) {
      const float4* ap = (const float4*)(A + (size_t)(brow + ar) * DF + k0 + ac);
      a0 = ap[0];
      a1 = ap[1];
    }
    const float4* wg = (const float4*)(W + (size_t)k0 * DF);
    float4 w0 = wg[tid], w1 = wg[tid + 256], w2 = wg[tid + 512], w3 = wg[tid + 768];

    __syncthreads();

    As[ac + 0][ar] = a0.x; As[ac + 1][ar] = a0.y;
    As[ac + 2][ar] = a0.z; As[ac + 3][ar] = a0.w;
    As[ac + 4][ar] = a1.x; As[ac + 5][ar] = a1.y;
    As[ac + 6][ar] = a1.z; As[ac + 7][ar] = a1.w;

    float4* wl = (float4*)&Ws[0][0];
    wl[tid] = w0; wl[tid + 256] = w1; wl[tid + 512] = w2; wl[tid + 768] = w3;

    __syncthreads();

#pragma unroll 4
    for (int kk = 0; kk < BK; ++kk) {
      float4 av0 = *(const float4*)&As[kk][rg * 8];
      float4 av1 = *(const float4*)&As[kk][rg * 8 + 4];
      float4 wv = *(const float4*)&Ws[kk][cg * 4];
      float a_[8] = {av0.x, av0.y, av0.z, av0.w, av1.x, av1.y, av1.z, av1.w};
#pragma unroll
      for (int r = 0; r < 8; ++r) {
        acc[r].x = fmaf(a_[r], wv.x, acc[r].x);
        acc[r].y = fmaf(a_[r], wv.y, acc[r].y);
        acc[r].z = fmaf(a_[r], wv.z, acc[r].z);
        acc[r].w = fmaf(a_[r], wv.w, acc[r].w);
      }
    }
  }

#pragma unroll
  for (int r = 0; r < 8; ++r) {
    int row = brow + rg * 8 + r;
    if (row < NN) {
      uint2 p;
      p.x = bf16rne(acc[r].x) | (bf16rne(acc[r].y) << 16);
      p.y = bf16rne(acc[r].z) | (bf16rne(acc[r].w) << 16);
      *(uint2*)(C + (size_t)row * (DF / 2) + cg * 2) = p;
    }
  }
}

// ---------------- Aggregation: one wave per node; 2 quarter-gathers in flight ----------------

__global__ __launch_bounds__(256) void k_agg(const unsigned* __restrict__ h, const float* __restrict__ dinv,
                                             const int* __restrict__ off, const int* __restrict__ ssrc,
                                             const float* __restrict__ bias,
                                             float* __restrict__ out, int do_relu) {
  int gw = (blockIdx.x * 256 + threadIdx.x) >> 6;
  int lane = threadIdx.x & 63;
  if (gw >= NN) return;

  int c = lane & 15;   // 16B chunk within row
  int q = lane >> 4;   // quarter id

  float di = dinv[gw];

  float acc[8];
  {
    float w = (q == 0) ? di * di : 0.f;
    uint4 u = *((const uint4*)(h + (size_t)gw * 64) + c);
    acc[0] = bflo(u.x) * w; acc[1] = bfhi(u.x) * w;
    acc[2] = bflo(u.y) * w; acc[3] = bfhi(u.y) * w;
    acc[4] = bflo(u.z) * w; acc[5] = bfhi(u.z) * w;
    acc[6] = bflo(u.w) * w; acc[7] = bfhi(u.w) * w;
  }

  int e = off[gw], e1 = off[gw + 1];
  int last = e1 - 1;
  for (int e0 = e; e0 < e1; e0 += 8) {
    int ea = e0 + q;
    int eb = e0 + 4 + q;
    int ia = min(ea, last), ib = min(eb, last);
    int sa = ssrc[ia];
    int sb = ssrc[ib];
    float wa = (ea < e1) ? dinv[sa] * di : 0.f;
    float wb = (eb < e1) ? dinv[sb] * di : 0.f;
    uint4 ua = *((const uint4*)(h + (size_t)sa * 64) + c);
    uint4 ub = *((const uint4*)(h + (size_t)sb * 64) + c);
    acc[0] = fmaf(bflo(ua.x), wa, acc[0]); acc[1] = fmaf(bfhi(ua.x), wa, acc[1]);
    acc[2] = fmaf(bflo(ua.y), wa, acc[2]); acc[3] = fmaf(bfhi(ua.y), wa, acc[3]);
    acc[4] = fmaf(bflo(ua.z), wa, acc[4]); acc[5] = fmaf(bfhi(ua.z), wa, acc[5]);
    acc[6] = fmaf(bflo(ua.w), wa, acc[6]); acc[7] = fmaf(bfhi(ua.w), wa, acc[7]);
    acc[0] = fmaf(bflo(ub.x), wb, acc[0]); acc[1] = fmaf(bfhi(ub.x), wb, acc[1]);
    acc[2] = fmaf(bflo(ub.y), wb, acc[2]); acc[3] = fmaf(bfhi(ub.y), wb, acc[3]);
    acc[4] = fmaf(bflo(ub.z), wb, acc[4]); acc[5] = fmaf(bfhi(ub.z), wb, acc[5]);
    acc[6] = fmaf(bflo(ub.w), wb, acc[6]); acc[7] = fmaf(bfhi(ub.w), wb, acc[7]);
  }

#pragma unroll
  for (int j = 0; j < 8; ++j) {
    acc[j] += __shfl_xor(acc[j], 16);
    acc[j] += __shfl_xor(acc[j], 32);
  }

  if (q < 2) {
    int col0 = c * 8 + q * 4;
    float4 b4 = *(const float4*)(bias + col0);
    float4 o;
    o.x = acc[q * 4 + 0] + b4.x;
    o.y = acc[q * 4 + 1] + b4.y;
    o.z = acc[q * 4 + 2] + b4.z;
    o.w = acc[q * 4 + 3] + b4.w;
    if (do_relu) {
      o.x = fmaxf(o.x, 0.f); o.y = fmaxf(o.y, 0.f);
      o.z = fmaxf(o.z, 0.f); o.w = fmaxf(o.w, 0.f);
    }
    *(float4*)(out + (size_t)gw * DF + col0) = o;
  }
}

// ---------------- launcher ----------------

extern "C" void kernel_launch(void* const* d_in, const int* in_sizes, int n_in,
                              void* d_out, int out_size, void* d_ws, size_t ws_size,
                              hipStream_t stream) {
  const float* x  = (const float*)d_in[0];
  const int*   ei = (const int*)d_in[1];
  const float* W1 = (const float*)d_in[2];
  const float* b1 = (const float*)d_in[3];
  const float* W2 = (const float*)d_in[4];
  const float* b2 = (const float*)d_in[5];
  float* out = (float*)d_out;

  char* ws = (char*)d_ws;
  unsigned* hT    = (unsigned*)ws; ws += (size_t)NN * (DF / 2) * 4;   // 12.8 MB bf16 table
  unsigned* pairs = (unsigned*)ws; ws += (size_t)NBKT * BSTRIDE * 4;  // 6.4 MB bucket staging
  int*   ssrc = (int*)ws;   ws += (size_t)NE * 4;
  float* dinv = (float*)ws; ws += (size_t)NN * 4;
  int*   off  = (int*)ws;   ws += (size_t)(NN + 1) * 4;
  int*   gfill= (int*)ws;   ws += (size_t)NBKT * CPAD * 4;            // line-padded counters
  int*   boff = (int*)ws;   ws += (size_t)(NBKT + 1) * 4;
  float* act = out;  // layer-1 activation (f32) in d_out; fully rewritten by final agg

  k_zb<<<1, 512, 0, stream>>>(gfill);
  k_bscatter<<<(NE + EPB - 1) / EPB, TPB, 0, stream>>>(ei, gfill, pairs);
  k_bscan<<<1, 512, 0, stream>>>(gfill, boff);
  k_build<<<NBKT, 256, 0, stream>>>(pairs, boff, off, dinv, ssrc);

  k_gemm<<<(NN + BM - 1) / BM, 256, 0, stream>>>(x, W1, hT);
  k_agg<<<(NN * 64 + 255) / 256, 256, 0, stream>>>(hT, dinv, off, ssrc, b1, act, 1);
  k_gemm<<<(NN + BM - 1) / BM, 256, 0, stream>>>(act, W2, hT);
  k_agg<<<(NN * 64 + 255) / 256, 256, 0, stream>>>(hT, dinv, off, ssrc, b2, out, 0);
}

// Round 11
// 163.382 us; speedup vs baseline: 2.3480x; 1.0179x over previous
//
#include <hip/hip_runtime.h>

#define NN 50000
#define NE 640000
#define DF 128
#define BM 64
#define BK 32
#define BSH 7
#define BWD 128                          // nodes per bucket
#define NBKT ((NN + BWD - 1) / BWD)      // 391 buckets
#define BSTRIDE 4096                     // per-bucket capacity (mean 1638)
#define CPAD 16                          // ints per global counter: one 64B line
#define EPB 8192                         // edges per bscatter block
#define TPB 512

__device__ inline unsigned bf16rne(float f) {
  unsigned u = __float_as_uint(f);
  return (u + 0x7fff + ((u >> 16) & 1)) >> 16;
}
__device__ inline float bflo(unsigned u) { return __uint_as_float(u << 16); }
__device__ inline float bfhi(unsigned u) { return __uint_as_float(u & 0xffff0000u); }

// ---------------- bucketed CSR build ----------------

__global__ __launch_bounds__(512) void k_zb(int* __restrict__ gfill) {
  for (int i = threadIdx.x; i < NBKT * CPAD; i += 512) gfill[i] = 0;
}

__global__ __launch_bounds__(512) void k_bscatter(const int* __restrict__ ei, int* __restrict__ gfill,
                                                  unsigned* __restrict__ pairs) {
  __shared__ int cnt[NBKT];
  __shared__ int cur[NBKT];
  __shared__ int gbase[NBKT];
  __shared__ int scan[TPB];
  __shared__ unsigned stage[EPB];
  int t = threadIdx.x;
  int e0 = blockIdx.x * EPB;

  for (int i = t; i < NBKT; i += TPB) cnt[i] = 0;
  __syncthreads();

  unsigned pk[16];
  int bk[16];
#pragma unroll
  for (int i = 0; i < 16; ++i) {
    int e = e0 + i * TPB + t;
    if (e < NE) {
      int s = ei[e], d = ei[NE + e];
      bk[i] = d >> BSH;
      pk[i] = (unsigned)s | ((unsigned)(d & (BWD - 1)) << 16);
      atomicAdd(&cnt[bk[i]], 1);
    } else {
      bk[i] = -1;
    }
  }
  __syncthreads();

  int v = (t < NBKT) ? cnt[t] : 0;
  scan[t] = v;
  __syncthreads();
  for (int d = 1; d < TPB; d <<= 1) {
    int x = (t >= d) ? scan[t - d] : 0;
    __syncthreads();
    scan[t] += x;
    __syncthreads();
  }
  if (t < NBKT) {
    int start = scan[t] - v;
    cnt[t] = start;
    cur[t] = start;
    gbase[t] = (v > 0) ? atomicAdd(&gfill[t * CPAD], v) : 0;
  }
  __syncthreads();

#pragma unroll
  for (int i = 0; i < 16; ++i) {
    if (bk[i] >= 0) {
      int pos = atomicAdd(&cur[bk[i]], 1);
      stage[pos] = pk[i];
    }
  }
  __syncthreads();

  int wv = t >> 6, ln = t & 63;
  for (int b = wv; b < NBKT; b += 8) {
    int start = cnt[b];
    int end = cur[b];
    int gb = gbase[b];
    unsigned* pb = pairs + (size_t)b * BSTRIDE;
    for (int i = start + ln; i < end; i += 64) {
      int go = gb + (i - start);
      if (go < BSTRIDE) pb[go] = stage[i];
    }
  }
}

__global__ __launch_bounds__(512) void k_bscan(const int* __restrict__ gfill, int* __restrict__ boff) {
  __shared__ int s[512];
  int t = threadIdx.x;
  int v = (t < NBKT) ? min(gfill[t * CPAD], BSTRIDE) : 0;
  s[t] = v;
  __syncthreads();
  for (int d = 1; d < 512; d <<= 1) {
    int x = (t >= d) ? s[t - d] : 0;
    __syncthreads();
    s[t] += x;
    __syncthreads();
  }
  if (t < NBKT) boff[t] = s[t] - v;
  if (t == 511) boff[NBKT] = s[511];
}

__global__ __launch_bounds__(256) void k_build(const unsigned* __restrict__ pairs,
                                               const int* __restrict__ boff,
                                               int* __restrict__ off, float* __restrict__ dinv,
                                               unsigned short* __restrict__ ssrc) {
  __shared__ int lcnt[BWD];
  __shared__ int lfill[BWD];
  __shared__ int s[BWD];
  __shared__ unsigned short stage[BSTRIDE];
  int b = blockIdx.x, t = threadIdx.x;
  int e0 = boff[b];
  int n = boff[b + 1] - e0;
  const unsigned* pb = pairs + (size_t)b * BSTRIDE;

  if (t < BWD) lcnt[t] = 0;
  __syncthreads();
  for (int i = t; i < n; i += 256) atomicAdd(&lcnt[pb[i] >> 16], 1);
  __syncthreads();

  int cnt = (t < BWD) ? lcnt[t] : 0;
  if (t < BWD) s[t] = cnt;
  __syncthreads();
  for (int d = 1; d < BWD; d <<= 1) {
    int x = (t >= d && t < BWD) ? s[t - d] : 0;
    __syncthreads();
    if (t < BWD) s[t] += x;
    __syncthreads();
  }
  int node = b * BWD + t;
  if (t < BWD) {
    int ex = s[t] - cnt;
    lfill[t] = ex;
    if (node < NN) {
      off[node] = e0 + ex;
      dinv[node] = rsqrtf((float)(cnt + 1));  // +1 self-loop
    }
    if (node == NN - 1) off[NN] = NE;
  }
  __syncthreads();

  for (int i = t; i < n; i += 256) {
    unsigned p = pb[i];
    int pos = atomicAdd(&lfill[p >> 16], 1);
    stage[pos] = (unsigned short)(p & 0xffffu);  // src < 50000 fits 16 bits
  }
  __syncthreads();
  for (int i = t; i < n; i += 256) ssrc[e0 + i] = stage[i];
}

// ---------------- GEMM: C_bf16[row] = dinv[row] * (A[row] @ W); row NN = zeros ----------------

template <int ABF16>
__global__ __launch_bounds__(256) void k_gemm(const void* __restrict__ Av,
                                              const float* __restrict__ W,
                                              const float* __restrict__ dinv,
                                              unsigned* __restrict__ C) {
  __shared__ float As[BK][BM + 4];
  __shared__ float Ws[BK][DF];

  int tid = threadIdx.x;
  int brow = blockIdx.x * BM;

  int rg = tid >> 5;
  int cg = tid & 31;
  int ar = tid >> 2;
  int ac = (tid & 3) * 8;

  float4 acc[8];
#pragma unroll
  for (int r = 0; r < 8; ++r) acc[r] = make_float4(0.f, 0.f, 0.f, 0.f);

  for (int k0 = 0; k0 < DF; k0 += BK) {
    float a[8] = {0.f, 0.f, 0.f, 0.f, 0.f, 0.f, 0.f, 0.f};
    if (brow + ar < NN) {
      if (ABF16) {
        const unsigned* ap = (const unsigned*)Av + (size_t)(brow + ar) * (DF / 2) + (k0 + ac) / 2;
        uint4 u = *(const uint4*)ap;
        a[0] = bflo(u.x); a[1] = bfhi(u.x); a[2] = bflo(u.y); a[3] = bfhi(u.y);
        a[4] = bflo(u.z); a[5] = bfhi(u.z); a[6] = bflo(u.w); a[7] = bfhi(u.w);
      } else {
        const float4* ap = (const float4*)((const float*)Av + (size_t)(brow + ar) * DF + k0 + ac);
        float4 a0 = ap[0], a1 = ap[1];
        a[0] = a0.x; a[1] = a0.y; a[2] = a0.z; a[3] = a0.w;
        a[4] = a1.x; a[5] = a1.y; a[6] = a1.z; a[7] = a1.w;
      }
    }
    const float4* wg = (const float4*)(W + (size_t)k0 * DF);
    float4 w0 = wg[tid], w1 = wg[tid + 256], w2 = wg[tid + 512], w3 = wg[tid + 768];

    __syncthreads();

#pragma unroll
    for (int j = 0; j < 8; ++j) As[ac + j][ar] = a[j];

    float4* wl = (float4*)&Ws[0][0];
    wl[tid] = w0; wl[tid + 256] = w1; wl[tid + 512] = w2; wl[tid + 768] = w3;

    __syncthreads();

#pragma unroll 4
    for (int kk = 0; kk < BK; ++kk) {
      float4 av0 = *(const float4*)&As[kk][rg * 8];
      float4 av1 = *(const float4*)&As[kk][rg * 8 + 4];
      float4 wv = *(const float4*)&Ws[kk][cg * 4];
      float a_[8] = {av0.x, av0.y, av0.z, av0.w, av1.x, av1.y, av1.z, av1.w};
#pragma unroll
      for (int r = 0; r < 8; ++r) {
        acc[r].x = fmaf(a_[r], wv.x, acc[r].x);
        acc[r].y = fmaf(a_[r], wv.y, acc[r].y);
        acc[r].z = fmaf(a_[r], wv.z, acc[r].z);
        acc[r].w = fmaf(a_[r], wv.w, acc[r].w);
      }
    }
  }

#pragma unroll
  for (int r = 0; r < 8; ++r) {
    int row = brow + rg * 8 + r;
    if (row <= NN) {
      float sc = (row < NN) ? dinv[row] : 0.f;  // row NN = reserved zero row
      uint2 p;
      p.x = bf16rne(acc[r].x * sc) | (bf16rne(acc[r].y * sc) << 16);
      p.y = bf16rne(acc[r].z * sc) | (bf16rne(acc[r].w * sc) << 16);
      *(uint2*)(C + (size_t)row * (DF / 2) + cg * 2) = p;
    }
  }
}

// ---------------- Aggregation: weightless gather+add; final scale by dinv[dst] ----------------
// out[d] = dinv[d] * (sum_e h'[src_e] + h'[d]) + bias;  h' table is dinv-prescaled bf16.
// OOB lanes gather reserved zero row NN. OUTBF16 also applies relu (layer 1).

template <int OUTBF16>
__global__ __launch_bounds__(256) void k_agg(const unsigned* __restrict__ h, const float* __restrict__ dinv,
                                             const int* __restrict__ off, const unsigned short* __restrict__ ssrc,
                                             const float* __restrict__ bias, void* __restrict__ out) {
  int gw = (blockIdx.x * 256 + threadIdx.x) >> 6;
  int lane = threadIdx.x & 63;
  if (gw >= NN) return;

  int c = lane & 15;   // 16B chunk within row
  int q = lane >> 4;   // quarter id

  float acc[8];
  {
    uint4 u = *((const uint4*)(h + (size_t)gw * 64) + c);  // self row (broadcast)
    float m = (q == 0) ? 1.f : 0.f;
    acc[0] = bflo(u.x) * m; acc[1] = bfhi(u.x) * m;
    acc[2] = bflo(u.y) * m; acc[3] = bfhi(u.y) * m;
    acc[4] = bflo(u.z) * m; acc[5] = bfhi(u.z) * m;
    acc[6] = bflo(u.w) * m; acc[7] = bfhi(u.w) * m;
  }

  int e = off[gw], e1 = off[gw + 1];
  for (int e0 = e; e0 < e1; e0 += 8) {
    int ea = e0 + q;
    int eb = e0 + 4 + q;
    int sa = (ea < e1) ? (int)ssrc[ea] : NN;   // zero row when OOB
    int sb = (eb < e1) ? (int)ssrc[eb] : NN;
    uint4 ua = *((const uint4*)(h + (size_t)sa * 64) + c);
    uint4 ub = *((const uint4*)(h + (size_t)sb * 64) + c);
    acc[0] += bflo(ua.x); acc[1] += bfhi(ua.x);
    acc[2] += bflo(ua.y); acc[3] += bfhi(ua.y);
    acc[4] += bflo(ua.z); acc[5] += bfhi(ua.z);
    acc[6] += bflo(ua.w); acc[7] += bfhi(ua.w);
    acc[0] += bflo(ub.x); acc[1] += bfhi(ub.x);
    acc[2] += bflo(ub.y); acc[3] += bfhi(ub.y);
    acc[4] += bflo(ub.z); acc[5] += bfhi(ub.z);
    acc[6] += bflo(ub.w); acc[7] += bfhi(ub.w);
  }

#pragma unroll
  for (int j = 0; j < 8; ++j) {
    acc[j] += __shfl_xor(acc[j], 16);
    acc[j] += __shfl_xor(acc[j], 32);
  }

  if (q < 2) {
    float di = dinv[gw];
    int col0 = c * 8 + q * 4;
    float4 b4 = *(const float4*)(bias + col0);
    float o0 = fmaf(acc[q * 4 + 0], di, b4.x);
    float o1 = fmaf(acc[q * 4 + 1], di, b4.y);
    float o2 = fmaf(acc[q * 4 + 2], di, b4.z);
    float o3 = fmaf(acc[q * 4 + 3], di, b4.w);
    if (OUTBF16) {
      o0 = fmaxf(o0, 0.f); o1 = fmaxf(o1, 0.f);
      o2 = fmaxf(o2, 0.f); o3 = fmaxf(o3, 0.f);
      uint2 p;
      p.x = bf16rne(o0) | (bf16rne(o1) << 16);
      p.y = bf16rne(o2) | (bf16rne(o3) << 16);
      *(uint2*)((unsigned*)out + (size_t)gw * (DF / 2) + c * 4 + q * 2) = p;
    } else {
      float4 o = make_float4(o0, o1, o2, o3);
      *(float4*)((float*)out + (size_t)gw * DF + col0) = o;
    }
  }
}

// ---------------- launcher ----------------

extern "C" void kernel_launch(void* const* d_in, const int* in_sizes, int n_in,
                              void* d_out, int out_size, void* d_ws, size_t ws_size,
                              hipStream_t stream) {
  const float* x  = (const float*)d_in[0];
  const int*   ei = (const int*)d_in[1];
  const float* W1 = (const float*)d_in[2];
  const float* b1 = (const float*)d_in[3];
  const float* W2 = (const float*)d_in[4];
  const float* b2 = (const float*)d_in[5];
  float* out = (float*)d_out;

  char* ws = (char*)d_ws;
  unsigned* hT    = (unsigned*)ws; ws += (size_t)(NN + 1) * (DF / 2) * 4;  // bf16 table + zero row
  unsigned* act   = (unsigned*)ws; ws += (size_t)(NN + 1) * (DF / 2) * 4;  // bf16 layer-1 activation
  unsigned* pairs = (unsigned*)ws; ws += (size_t)NBKT * BSTRIDE * 4;
  int*   off  = (int*)ws;   ws += (size_t)(NN + 1) * 4;
  int*   gfill= (int*)ws;   ws += (size_t)NBKT * CPAD * 4;
  int*   boff = (int*)ws;   ws += (size_t)(NBKT + 1) * 4;
  float* dinv = (float*)ws; ws += (size_t)NN * 4;
  unsigned short* ssrc = (unsigned short*)ws; ws += ((size_t)NE + 16) * 2;

  const int GGRID = (NN + 1 + BM - 1) / BM;  // covers zero row NN

  k_zb<<<1, 512, 0, stream>>>(gfill);
  k_bscatter<<<(NE + EPB - 1) / EPB, TPB, 0, stream>>>(ei, gfill, pairs);
  k_bscan<<<1, 512, 0, stream>>>(gfill, boff);
  k_build<<<NBKT, 256, 0, stream>>>(pairs, boff, off, dinv, ssrc);

  k_gemm<0><<<GGRID, 256, 0, stream>>>(x, W1, dinv, hT);
  k_agg<1><<<(NN * 64 + 255) / 256, 256, 0, stream>>>(hT, dinv, off, ssrc, b1, act);
  k_gemm<1><<<GGRID, 256, 0, stream>>>(act, W2, dinv, hT);
  k_agg<0><<<(NN * 64 + 255) / 256, 256, 0, stream>>>(hT, dinv, off, ssrc, b2, out);
}

// Round 12
// 138.779 us; speedup vs baseline: 2.7642x; 1.1773x over previous
//
#include <hip/hip_runtime.h>

#define NN 50000
#define NE 640000
#define DF 128
#define BM 64
#define BSH 7
#define BWD 128
#define NBKT ((NN + BWD - 1) / BWD)      // 391 buckets
#define BSTRIDE 4096
#define CPAD 16
#define EPB 8192
#define TPB 512
#define MROWS 50048                      // 782*64 rows in padded tables

typedef __attribute__((ext_vector_type(8))) short short8;
typedef __attribute__((ext_vector_type(4))) float f32x4;

__device__ inline unsigned bf16rne(float f) {
  unsigned u = __float_as_uint(f);
  return (u + 0x7fff + ((u >> 16) & 1)) >> 16;
}
__device__ inline float bflo(unsigned u) { return __uint_as_float(u << 16); }
__device__ inline float bfhi(unsigned u) { return __uint_as_float(u & 0xffff0000u); }
__device__ inline float bfs(unsigned short h) { return __uint_as_float(((unsigned)h) << 16); }

// ---------------- bucketed CSR build (unchanged from r10/r11) ----------------

__global__ __launch_bounds__(512) void k_zb(int* __restrict__ gfill) {
  for (int i = threadIdx.x; i < NBKT * CPAD; i += 512) gfill[i] = 0;
}

__global__ __launch_bounds__(512) void k_bscatter(const int* __restrict__ ei, int* __restrict__ gfill,
                                                  unsigned* __restrict__ pairs) {
  __shared__ int cnt[NBKT];
  __shared__ int cur[NBKT];
  __shared__ int gbase[NBKT];
  __shared__ int scan[TPB];
  __shared__ unsigned stage[EPB];
  int t = threadIdx.x;
  int e0 = blockIdx.x * EPB;

  for (int i = t; i < NBKT; i += TPB) cnt[i] = 0;
  __syncthreads();

  unsigned pk[16];
  int bk[16];
#pragma unroll
  for (int i = 0; i < 16; ++i) {
    int e = e0 + i * TPB + t;
    if (e < NE) {
      int s = ei[e], d = ei[NE + e];
      bk[i] = d >> BSH;
      pk[i] = (unsigned)s | ((unsigned)(d & (BWD - 1)) << 16);
      atomicAdd(&cnt[bk[i]], 1);
    } else {
      bk[i] = -1;
    }
  }
  __syncthreads();

  int v = (t < NBKT) ? cnt[t] : 0;
  scan[t] = v;
  __syncthreads();
  for (int d = 1; d < TPB; d <<= 1) {
    int x = (t >= d) ? scan[t - d] : 0;
    __syncthreads();
    scan[t] += x;
    __syncthreads();
  }
  if (t < NBKT) {
    int start = scan[t] - v;
    cnt[t] = start;
    cur[t] = start;
    gbase[t] = (v > 0) ? atomicAdd(&gfill[t * CPAD], v) : 0;
  }
  __syncthreads();

#pragma unroll
  for (int i = 0; i < 16; ++i) {
    if (bk[i] >= 0) {
      int pos = atomicAdd(&cur[bk[i]], 1);
      stage[pos] = pk[i];
    }
  }
  __syncthreads();

  int wv = t >> 6, ln = t & 63;
  for (int b = wv; b < NBKT; b += 8) {
    int start = cnt[b];
    int end = cur[b];
    int gb = gbase[b];
    unsigned* pb = pairs + (size_t)b * BSTRIDE;
    for (int i = start + ln; i < end; i += 64) {
      int go = gb + (i - start);
      if (go < BSTRIDE) pb[go] = stage[i];
    }
  }
}

__global__ __launch_bounds__(512) void k_bscan(const int* __restrict__ gfill, int* __restrict__ boff) {
  __shared__ int s[512];
  int t = threadIdx.x;
  int v = (t < NBKT) ? min(gfill[t * CPAD], BSTRIDE) : 0;
  s[t] = v;
  __syncthreads();
  for (int d = 1; d < 512; d <<= 1) {
    int x = (t >= d) ? s[t - d] : 0;
    __syncthreads();
    s[t] += x;
    __syncthreads();
  }
  if (t < NBKT) boff[t] = s[t] - v;
  if (t == 511) boff[NBKT] = s[511];
}

__global__ __launch_bounds__(256) void k_build(const unsigned* __restrict__ pairs,
                                               const int* __restrict__ boff,
                                               int* __restrict__ off, float* __restrict__ dinv,
                                               unsigned short* __restrict__ ssrc) {
  __shared__ int lcnt[BWD];
  __shared__ int lfill[BWD];
  __shared__ int s[BWD];
  __shared__ unsigned short stage[BSTRIDE];
  int b = blockIdx.x, t = threadIdx.x;
  int e0 = boff[b];
  int n = boff[b + 1] - e0;
  const unsigned* pb = pairs + (size_t)b * BSTRIDE;

  if (t < BWD) lcnt[t] = 0;
  __syncthreads();
  for (int i = t; i < n; i += 256) atomicAdd(&lcnt[pb[i] >> 16], 1);
  __syncthreads();

  int cnt = (t < BWD) ? lcnt[t] : 0;
  if (t < BWD) s[t] = cnt;
  __syncthreads();
  for (int d = 1; d < BWD; d <<= 1) {
    int x = (t >= d && t < BWD) ? s[t - d] : 0;
    __syncthreads();
    if (t < BWD) s[t] += x;
    __syncthreads();
  }
  int node = b * BWD + t;
  if (t < BWD) {
    int ex = s[t] - cnt;
    lfill[t] = ex;
    if (node < NN) {
      off[node] = e0 + ex;
      dinv[node] = rsqrtf((float)(cnt + 1));  // +1 self-loop
    }
    if (node == NN - 1) off[NN] = NE;
  }
  __syncthreads();

  for (int i = t; i < n; i += 256) {
    unsigned p = pb[i];
    int pos = atomicAdd(&lfill[p >> 16], 1);
    stage[pos] = (unsigned short)(p & 0xffffu);
  }
  __syncthreads();
  for (int i = t; i < n; i += 256) ssrc[e0 + i] = stage[i];
}

// ---------------- W fragment pack: [mat][ct=8][kc=4][lane=64] of 8 bf16 hi/lo ----------------
// B-frag mapping: lane l holds W[k = kc*32 + (l>>4)*8 + j][col = ct*16 + (l&15)], j=0..7.

__global__ __launch_bounds__(256) void k_wpack(const float* __restrict__ W1, const float* __restrict__ W2,
                                               uint4* __restrict__ whf, uint4* __restrict__ wlf) {
  int idx = blockIdx.x * 256 + threadIdx.x;  // 0..4095
  if (idx >= 4096) return;
  int m = idx >> 11;
  int r = idx & 2047;
  int ct = r >> 8, kc = (r >> 6) & 3, l = r & 63;
  const float* W = m ? W2 : W1;
  unsigned hi[8], lo[8];
#pragma unroll
  for (int j = 0; j < 8; ++j) {
    int k = kc * 32 + (l >> 4) * 8 + j;
    int c = ct * 16 + (l & 15);
    float w = W[k * DF + c];
    unsigned h = bf16rne(w);
    hi[j] = h;
    lo[j] = bf16rne(w - bflo(h));
  }
  uint4 H, L;
  H.x = hi[0] | (hi[1] << 16); H.y = hi[2] | (hi[3] << 16);
  H.z = hi[4] | (hi[5] << 16); H.w = hi[6] | (hi[7] << 16);
  L.x = lo[0] | (lo[1] << 16); L.y = lo[2] | (lo[3] << 16);
  L.z = lo[4] | (lo[5] << 16); L.w = lo[6] | (lo[7] << 16);
  whf[idx] = H;
  wlf[idx] = L;
}

// ---------------- MFMA GEMM: C_bf16[row] = dinv[row] * (A[row] @ W) ----------------
// Wave = 16 rows x 128 cols. A-frag: row=l&15, k=(l>>4)*8+j. D: row=(l>>4)*4+reg, col=l&15.
// Hi/lo split: AhWh + AhWl (+ AlWh when A is f32) keeps error at f32-level.

template <int ABF16>
__global__ __launch_bounds__(256) void k_gemm(const void* __restrict__ Av,
                                              const uint4* __restrict__ whf,
                                              const uint4* __restrict__ wlf,
                                              const float* __restrict__ dinv,
                                              unsigned* __restrict__ C) {
  __shared__ float Ep[4][16][132];
  int t = threadIdx.x, w = t >> 6, l = t & 63;
  int brow = blockIdx.x * BM + w * 16;
  int ra = brow + (l & 15);
  bool inb = ra < NN;

  short8 Ah[4], Al[4];
#pragma unroll
  for (int kc = 0; kc < 4; ++kc) {
    if (ABF16) {
      uint4 u = make_uint4(0, 0, 0, 0);
      if (inb) u = ((const uint4*)Av)[(size_t)ra * 16 + kc * 4 + (l >> 4)];
      Ah[kc] = *(short8*)&u;
      Al[kc] = short8{0, 0, 0, 0, 0, 0, 0, 0};
    } else {
      float f[8] = {0.f, 0.f, 0.f, 0.f, 0.f, 0.f, 0.f, 0.f};
      if (inb) {
        const float* A = (const float*)Av + (size_t)ra * DF + kc * 32 + (l >> 4) * 8;
        float4 p = *(const float4*)A;
        float4 q = *(const float4*)(A + 4);
        f[0] = p.x; f[1] = p.y; f[2] = p.z; f[3] = p.w;
        f[4] = q.x; f[5] = q.y; f[6] = q.z; f[7] = q.w;
      }
      unsigned hh[8], ll[8];
#pragma unroll
      for (int j = 0; j < 8; ++j) {
        hh[j] = bf16rne(f[j]);
        ll[j] = bf16rne(f[j] - bflo(hh[j]));
      }
      uint4 H, L;
      H.x = hh[0] | (hh[1] << 16); H.y = hh[2] | (hh[3] << 16);
      H.z = hh[4] | (hh[5] << 16); H.w = hh[6] | (hh[7] << 16);
      L.x = ll[0] | (ll[1] << 16); L.y = ll[2] | (ll[3] << 16);
      L.z = ll[4] | (ll[5] << 16); L.w = ll[6] | (ll[7] << 16);
      Ah[kc] = *(short8*)&H;
      Al[kc] = *(short8*)&L;
    }
  }

  f32x4 acc[8];
#pragma unroll
  for (int ct = 0; ct < 8; ++ct) acc[ct] = f32x4{0.f, 0.f, 0.f, 0.f};

#pragma unroll
  for (int kc = 0; kc < 4; ++kc) {
#pragma unroll
    for (int ct = 0; ct < 8; ++ct) {
      int fi = (ct * 4 + kc) * 64 + l;
      uint4 wh4 = whf[fi];
      uint4 wl4 = wlf[fi];
      short8 wh = *(short8*)&wh4;
      short8 wl = *(short8*)&wl4;
      acc[ct] = __builtin_amdgcn_mfma_f32_16x16x32_bf16(Ah[kc], wh, acc[ct], 0, 0, 0);
      acc[ct] = __builtin_amdgcn_mfma_f32_16x16x32_bf16(Ah[kc], wl, acc[ct], 0, 0, 0);
      if (!ABF16)
        acc[ct] = __builtin_amdgcn_mfma_f32_16x16x32_bf16(Al[kc], wh, acc[ct], 0, 0, 0);
    }
  }

  // stage D to LDS: row=(l>>4)*4+reg, col=ct*16+(l&15)   (same-wave write/read; no barrier)
#pragma unroll
  for (int ct = 0; ct < 8; ++ct) {
#pragma unroll
    for (int reg = 0; reg < 4; ++reg)
      Ep[w][(l >> 4) * 4 + reg][ct * 16 + (l & 15)] = acc[ct][reg];
  }

  int r16 = l >> 2, cc = (l & 3) * 32;
  int R = blockIdx.x * BM + w * 16 + r16;
  float sc = (R < NN) ? dinv[R] : 0.f;
  unsigned ub[16];
#pragma unroll
  for (int i = 0; i < 16; ++i) {
    float f0 = Ep[w][r16][cc + 2 * i] * sc;
    float f1 = Ep[w][r16][cc + 2 * i + 1] * sc;
    ub[i] = bf16rne(f0) | (bf16rne(f1) << 16);
  }
  uint4* co = (uint4*)(C + (size_t)R * 64 + (cc >> 1));
  co[0] = make_uint4(ub[0], ub[1], ub[2], ub[3]);
  co[1] = make_uint4(ub[4], ub[5], ub[6], ub[7]);
  co[2] = make_uint4(ub[8], ub[9], ub[10], ub[11]);
  co[3] = make_uint4(ub[12], ub[13], ub[14], ub[15]);
}

// ---------------- Aggregation (unchanged r11): weightless gather+add ----------------

template <int OUTBF16>
__global__ __launch_bounds__(256) void k_agg(const unsigned* __restrict__ h, const float* __restrict__ dinv,
                                             const int* __restrict__ off, const unsigned short* __restrict__ ssrc,
                                             const float* __restrict__ bias, void* __restrict__ out) {
  int gw = (blockIdx.x * 256 + threadIdx.x) >> 6;
  int lane = threadIdx.x & 63;
  if (gw >= NN) return;

  int c = lane & 15;
  int q = lane >> 4;

  float acc[8];
  {
    uint4 u = *((const uint4*)(h + (size_t)gw * 64) + c);
    float m = (q == 0) ? 1.f : 0.f;
    acc[0] = bflo(u.x) * m; acc[1] = bfhi(u.x) * m;
    acc[2] = bflo(u.y) * m; acc[3] = bfhi(u.y) * m;
    acc[4] = bflo(u.z) * m; acc[5] = bfhi(u.z) * m;
    acc[6] = bflo(u.w) * m; acc[7] = bfhi(u.w) * m;
  }

  int e = off[gw], e1 = off[gw + 1];
  for (int e0 = e; e0 < e1; e0 += 8) {
    int ea = e0 + q;
    int eb = e0 + 4 + q;
    int sa = (ea < e1) ? (int)ssrc[ea] : NN;
    int sb = (eb < e1) ? (int)ssrc[eb] : NN;
    uint4 ua = *((const uint4*)(h + (size_t)sa * 64) + c);
    uint4 ub = *((const uint4*)(h + (size_t)sb * 64) + c);
    acc[0] += bflo(ua.x); acc[1] += bfhi(ua.x);
    acc[2] += bflo(ua.y); acc[3] += bfhi(ua.y);
    acc[4] += bflo(ua.z); acc[5] += bfhi(ua.z);
    acc[6] += bflo(ua.w); acc[7] += bfhi(ua.w);
    acc[0] += bflo(ub.x); acc[1] += bfhi(ub.x);
    acc[2] += bflo(ub.y); acc[3] += bfhi(ub.y);
    acc[4] += bflo(ub.z); acc[5] += bfhi(ub.z);
    acc[6] += bflo(ub.w); acc[7] += bfhi(ub.w);
  }

#pragma unroll
  for (int j = 0; j < 8; ++j) {
    acc[j] += __shfl_xor(acc[j], 16);
    acc[j] += __shfl_xor(acc[j], 32);
  }

  if (q < 2) {
    float di = dinv[gw];
    int col0 = c * 8 + q * 4;
    float4 b4 = *(const float4*)(bias + col0);
    float o0 = fmaf(acc[q * 4 + 0], di, b4.x);
    float o1 = fmaf(acc[q * 4 + 1], di, b4.y);
    float o2 = fmaf(acc[q * 4 + 2], di, b4.z);
    float o3 = fmaf(acc[q * 4 + 3], di, b4.w);
    if (OUTBF16) {
      o0 = fmaxf(o0, 0.f); o1 = fmaxf(o1, 0.f);
      o2 = fmaxf(o2, 0.f); o3 = fmaxf(o3, 0.f);
      uint2 p;
      p.x = bf16rne(o0) | (bf16rne(o1) << 16);
      p.y = bf16rne(o2) | (bf16rne(o3) << 16);
      *(uint2*)((unsigned*)out + (size_t)gw * (DF / 2) + c * 4 + q * 2) = p;
    } else {
      float4 o = make_float4(o0, o1, o2, o3);
      *(float4*)((float*)out + (size_t)gw * DF + col0) = o;
    }
  }
}

// ---------------- launcher ----------------

extern "C" void kernel_launch(void* const* d_in, const int* in_sizes, int n_in,
                              void* d_out, int out_size, void* d_ws, size_t ws_size,
                              hipStream_t stream) {
  const float* x  = (const float*)d_in[0];
  const int*   ei = (const int*)d_in[1];
  const float* W1 = (const float*)d_in[2];
  const float* b1 = (const float*)d_in[3];
  const float* W2 = (const float*)d_in[4];
  const float* b2 = (const float*)d_in[5];
  float* out = (float*)d_out;

  char* ws = (char*)d_ws;
  unsigned* hT    = (unsigned*)ws; ws += (size_t)MROWS * (DF / 2) * 4;  // bf16 table (padded rows)
  unsigned* act   = (unsigned*)ws; ws += (size_t)MROWS * (DF / 2) * 4;  // bf16 layer-1 activation
  unsigned* pairs = (unsigned*)ws; ws += (size_t)NBKT * BSTRIDE * 4;
  uint4* whf = (uint4*)ws;  ws += (size_t)4096 * 16;                    // W hi fragments (both mats)
  uint4* wlf = (uint4*)ws;  ws += (size_t)4096 * 16;                    // W lo fragments
  int*   off  = (int*)ws;   ws += (size_t)(NN + 1) * 4;
  int*   gfill= (int*)ws;   ws += (size_t)NBKT * CPAD * 4;
  int*   boff = (int*)ws;   ws += (size_t)(NBKT + 1) * 4;
  float* dinv = (float*)ws; ws += (size_t)NN * 4;
  unsigned short* ssrc = (unsigned short*)ws; ws += ((size_t)NE + 16) * 2;

  const int GGRID = MROWS / BM;  // 782

  k_zb<<<1, 512, 0, stream>>>(gfill);
  k_bscatter<<<(NE + EPB - 1) / EPB, TPB, 0, stream>>>(ei, gfill, pairs);
  k_bscan<<<1, 512, 0, stream>>>(gfill, boff);
  k_wpack<<<16, 256, 0, stream>>>(W1, W2, whf, wlf);
  k_build<<<NBKT, 256, 0, stream>>>(pairs, boff, off, dinv, ssrc);

  k_gemm<0><<<GGRID, 256, 0, stream>>>(x, whf, wlf, dinv, hT);
  k_agg<1><<<(NN * 64 + 255) / 256, 256, 0, stream>>>(hT, dinv, off, ssrc, b1, act);
  k_gemm<1><<<GGRID, 256, 0, stream>>>(act, whf + 2048, wlf + 2048, dinv, hT);
  k_agg<0><<<(NN * 64 + 255) / 256, 256, 0, stream>>>(hT, dinv, off, ssrc, b2, out);
}